// Round 1
// baseline (1818.575 us; speedup 1.0000x reference)
//
#include <hip/hip_runtime.h>
#include <math.h>

#define B_SZ 2
#define LSEQ 1024
#define D_INP 1024
#define D_MODEL 2048
#define D_STATE 16
#define D_DISCR 128
#define KER 4
#define MROWS (B_SZ * LSEQ)  // 2048 rows for all GEMMs

__device__ __forceinline__ float siluf(float x) { return x / (1.f + expf(-x)); }
__device__ __forceinline__ float softplusf(float x) {
    return fmaxf(x, 0.f) + log1pf(expf(-fabsf(x)));
}

// C[M,N] = A[M,K] @ Bw[N,K]^T   (all fp32, row-major, weights stored [N,K])
// A row stride = lda with column offset aoff; C row stride = ldc with offset coff.
// epi==1: C = softplus(bias[col] + acc)
__global__ __launch_bounds__(256) void gemm_nt(
    const float* __restrict__ A, int lda, int aoff,
    const float* __restrict__ Bw,
    float* __restrict__ C, int ldc, int coff,
    int N, int K,
    const float* __restrict__ bias, int epi)
{
    __shared__ float As[16][68];  // padded: rows 16B-aligned -> ds_read_b128
    __shared__ float Bs[16][68];
    const int tid = threadIdx.x;
    const int tx = tid & 15, ty = tid >> 4;
    const int row0 = blockIdx.y * 64, col0 = blockIdx.x * 64;

    float acc[4][4];
#pragma unroll
    for (int i = 0; i < 4; i++)
#pragma unroll
        for (int j = 0; j < 4; j++) acc[i][j] = 0.f;

    for (int k0 = 0; k0 < K; k0 += 16) {
#pragma unroll
        for (int i = tid; i < 1024; i += 256) {
            int r = i >> 4, kk = i & 15;
            As[kk][r] = A[(size_t)(row0 + r) * lda + aoff + k0 + kk];
        }
#pragma unroll
        for (int i = tid; i < 1024; i += 256) {
            int c = i >> 4, kk = i & 15;
            int col = col0 + c;
            Bs[kk][c] = (col < N) ? Bw[(size_t)col * K + k0 + kk] : 0.f;
        }
        __syncthreads();
#pragma unroll
        for (int kk = 0; kk < 16; kk++) {
            float a4[4], b4[4];
#pragma unroll
            for (int i = 0; i < 4; i++) a4[i] = As[kk][ty * 4 + i];
#pragma unroll
            for (int j = 0; j < 4; j++) b4[j] = Bs[kk][tx * 4 + j];
#pragma unroll
            for (int i = 0; i < 4; i++)
#pragma unroll
                for (int j = 0; j < 4; j++)
                    acc[i][j] = fmaf(a4[i], b4[j], acc[i][j]);
        }
        __syncthreads();
    }

#pragma unroll
    for (int i = 0; i < 4; i++) {
        int row = row0 + ty * 4 + i;  // M==2048, always in range
#pragma unroll
        for (int j = 0; j < 4; j++) {
            int col = col0 + tx * 4 + j;
            if (col < N) {
                float v = acc[i][j];
                if (epi == 1) v = softplusf(bias[col] + v);
                C[(size_t)row * ldc + coff + col] = v;
            }
        }
    }
}

// depthwise causal conv1d (KER=4, left pad 3) + bias + SiLU
// reads a = ab[:, 0:2048] (row stride 4096), writes aConv [MROWS, 2048]
__global__ __launch_bounds__(256) void conv_silu(
    const float* __restrict__ ab,
    const float* __restrict__ cw,   // [2048, 4]
    const float* __restrict__ cb,   // [2048]
    float* __restrict__ aConv)
{
    int idx = blockIdx.x * 256 + threadIdx.x;  // over MROWS*D_MODEL
    int d = idx & (D_MODEL - 1);
    int bl = idx >> 11;
    int l = bl & (LSEQ - 1);
    float w0 = cw[d * 4 + 0], w1 = cw[d * 4 + 1], w2 = cw[d * 4 + 2], w3 = cw[d * 4 + 3];
    const float* col = ab + (size_t)bl * 4096 + d;
    float acc = cb[d];
    acc = fmaf(col[0], w3, acc);                       // x[l]   * w[3]
    if (l >= 1) acc = fmaf(*(col - 4096), w2, acc);    // x[l-1] * w[2]
    if (l >= 2) acc = fmaf(*(col - 2 * 4096), w1, acc);
    if (l >= 3) acc = fmaf(*(col - 3 * 4096), w0, acc);
    aConv[idx] = siluf(acc);
}

// SSM scan fused with C-contraction, D-skip, and gate-SiLU.
// One thread per (b, d) chain; 16 states in registers; writes out in-place over delta.
__global__ __launch_bounds__(256) void ssm_scan(
    float* __restrict__ delta,        // [MROWS, 2048], overwritten with out
    const float* __restrict__ aConv,  // [MROWS, 2048]
    const float* __restrict__ ab,     // gate at [bl][2048+d], row stride 4096
    const float* __restrict__ bcd,    // [MROWS, 160]: B 0..15, C 16..31
    const float* __restrict__ A_param,  // [2048, 16]
    const float* __restrict__ D_param)  // [2048]
{
    int t = blockIdx.x * 256 + threadIdx.x;  // 0..4095
    int d = t & (D_MODEL - 1);
    int b = t >> 11;
    float expA[D_STATE];
#pragma unroll
    for (int s = 0; s < D_STATE; s++) expA[s] = expf(-A_param[d * D_STATE + s]);
    float Dp = D_param[d];
    float h[D_STATE];
#pragma unroll
    for (int s = 0; s < D_STATE; s++) h[s] = 0.f;

    size_t rbase = (size_t)b * LSEQ;
    for (int l = 0; l < LSEQ; l++) {
        size_t r = rbase + l;
        float dlt = delta[r * D_MODEL + d];
        float av = aConv[r * D_MODEL + d];
        float g = ab[r * 4096 + D_MODEL + d];
        const float* bc = bcd + r * 160;
        float x = dlt * av;
        float acc = 0.f;
#pragma unroll
        for (int s = 0; s < D_STATE; s++) {
            h[s] = fmaf(expA[s] * dlt, h[s], bc[s] * x);
            acc = fmaf(h[s], bc[16 + s], acc);
        }
        float o = (acc + Dp * av) * siluf(g);
        delta[r * D_MODEL + d] = o;  // in-place: becomes "out" for final GEMM
    }
}

extern "C" void kernel_launch(void* const* d_in, const int* in_sizes, int n_in,
                              void* d_out, int out_size, void* d_ws, size_t ws_size,
                              hipStream_t stream) {
    const float* seq = (const float*)d_in[0];
    const float* w_in = (const float*)d_in[1];
    const float* w_out = (const float*)d_in[2];
    const float* w_B = (const float*)d_in[3];
    const float* w_C = (const float*)d_in[4];
    const float* w_D1 = (const float*)d_in[5];
    const float* w_D2 = (const float*)d_in[6];
    const float* conv_w = (const float*)d_in[7];
    const float* conv_b = (const float*)d_in[8];
    const float* A_param = (const float*)d_in[9];
    const float* D_param = (const float*)d_in[10];
    float* out = (float*)d_out;

    // workspace layout (floats): total 2048*(4096+2048+160+2048) = 68.4 MB
    float* ab = (float*)d_ws;                     // [MROWS, 4096]  a | gate
    float* aConv = ab + (size_t)MROWS * 4096;     // [MROWS, 2048]
    float* bcd = aConv + (size_t)MROWS * 2048;    // [MROWS, 160]   B|C|d1
    float* delta = bcd + (size_t)MROWS * 160;     // [MROWS, 2048]  -> out (in-place)

    // 1) ab = seq @ w_in^T   [2048,1024]@[1024,4096]^T
    gemm_nt<<<dim3(64, 32), 256, 0, stream>>>(seq, D_INP, 0, w_in, ab, 4096, 0,
                                              4096, D_INP, nullptr, 0);
    // 2) depthwise conv + SiLU
    conv_silu<<<dim3((MROWS * D_MODEL) / 256), 256, 0, stream>>>(ab, conv_w, conv_b, aConv);
    // 3) Bm / Cm / d1 projections from aConv (K=2048)
    gemm_nt<<<dim3(1, 32), 256, 0, stream>>>(aConv, D_MODEL, 0, w_B, bcd, 160, 0,
                                             16, D_MODEL, nullptr, 0);
    gemm_nt<<<dim3(1, 32), 256, 0, stream>>>(aConv, D_MODEL, 0, w_C, bcd, 160, 16,
                                             16, D_MODEL, nullptr, 0);
    gemm_nt<<<dim3(2, 32), 256, 0, stream>>>(aConv, D_MODEL, 0, w_D1, bcd, 160, 32,
                                             D_DISCR, D_MODEL, nullptr, 0);
    // 4) delta = softplus(D_param + d1 @ w_D2^T)   K=128, N=2048
    gemm_nt<<<dim3(32, 32), 256, 0, stream>>>(bcd, 160, 32, w_D2, delta, D_MODEL, 0,
                                              D_MODEL, D_DISCR, D_param, 1);
    // 5) fused scan + C-contract + D-skip + gate (writes out into delta buffer)
    ssm_scan<<<dim3(16), 256, 0, stream>>>(delta, aConv, ab, bcd, A_param, D_param);
    // 6) result = out @ w_out^T   K=2048, N=1024
    gemm_nt<<<dim3(16, 32), 256, 0, stream>>>(delta, D_MODEL, 0, w_out, out, D_INP, 0,
                                              D_INP, D_MODEL, nullptr, 0);
}

// Round 2
// 937.005 us; speedup vs baseline: 1.9408x; 1.9408x over previous
//
#include <hip/hip_runtime.h>
#include <math.h>

#define B_SZ 2
#define LSEQ 1024
#define D_INP 1024
#define D_MODEL 2048
#define D_STATE 16
#define D_DISCR 128
#define MROWS (B_SZ * LSEQ)
#define NCH 16          // chunks per sequence
#define CH 64           // chunk length

__device__ __forceinline__ float siluf(float x) { return x / (1.f + expf(-x)); }
__device__ __forceinline__ float softplusf(float x) {
    return fmaxf(x, 0.f) + log1pf(expf(-fabsf(x)));
}

// ---------------------------------------------------------------------------
// 128x128 fp32 GEMM-NT: C[M,N] = A[M,K] @ Bw[N,K]^T, all dims % 128 == 0,
// K % 16 == 0. A row stride lda, col offset aoff. epi==1: softplus(bias+acc).
// 256 threads, 8x8 per thread.
__global__ __launch_bounds__(256) void gemm128(
    const float* __restrict__ A, int lda, int aoff,
    const float* __restrict__ Bw,
    float* __restrict__ C, int ldc,
    int K, const float* __restrict__ bias, int epi)
{
    __shared__ float As[16][132];
    __shared__ float Bs[16][132];
    const int tid = threadIdx.x;
    const int tx = tid & 15, ty = tid >> 4;
    const int row0 = blockIdx.y * 128, col0 = blockIdx.x * 128;
    const int lr = tid >> 1;            // 0..127 row/col within tile
    const int lk = (tid & 1) * 8;       // k sub-offset 0 or 8

    float acc[8][8];
#pragma unroll
    for (int i = 0; i < 8; i++)
#pragma unroll
        for (int j = 0; j < 8; j++) acc[i][j] = 0.f;

    for (int k0 = 0; k0 < K; k0 += 16) {
        // stage A: 128 rows x 16 k
        {
            const float* src = A + (size_t)(row0 + lr) * lda + aoff + k0 + lk;
            float4 v0 = *(const float4*)src;
            float4 v1 = *(const float4*)(src + 4);
            As[lk + 0][lr] = v0.x; As[lk + 1][lr] = v0.y;
            As[lk + 2][lr] = v0.z; As[lk + 3][lr] = v0.w;
            As[lk + 4][lr] = v1.x; As[lk + 5][lr] = v1.y;
            As[lk + 6][lr] = v1.z; As[lk + 7][lr] = v1.w;
        }
        // stage B: 128 cols x 16 k
        {
            const float* src = Bw + (size_t)(col0 + lr) * K + k0 + lk;
            float4 v0 = *(const float4*)src;
            float4 v1 = *(const float4*)(src + 4);
            Bs[lk + 0][lr] = v0.x; Bs[lk + 1][lr] = v0.y;
            Bs[lk + 2][lr] = v0.z; Bs[lk + 3][lr] = v0.w;
            Bs[lk + 4][lr] = v1.x; Bs[lk + 5][lr] = v1.y;
            Bs[lk + 6][lr] = v1.z; Bs[lk + 7][lr] = v1.w;
        }
        __syncthreads();
#pragma unroll
        for (int kk = 0; kk < 16; kk++) {
            float a8[8], b8[8];
            *(float4*)&a8[0] = *(const float4*)&As[kk][ty * 8];
            *(float4*)&a8[4] = *(const float4*)&As[kk][ty * 8 + 4];
            *(float4*)&b8[0] = *(const float4*)&Bs[kk][tx * 8];
            *(float4*)&b8[4] = *(const float4*)&Bs[kk][tx * 8 + 4];
#pragma unroll
            for (int i = 0; i < 8; i++)
#pragma unroll
                for (int j = 0; j < 8; j++)
                    acc[i][j] = fmaf(a8[i], b8[j], acc[i][j]);
        }
        __syncthreads();
    }

#pragma unroll
    for (int i = 0; i < 8; i++) {
        int row = row0 + ty * 8 + i;
        float* dst = C + (size_t)row * ldc + col0 + tx * 8;
        if (epi == 1) {
            const float* bp = bias + col0 + tx * 8;
#pragma unroll
            for (int j = 0; j < 8; j++) dst[j] = softplusf(bp[j] + acc[i][j]);
        } else {
            float4 o0 = {acc[i][0], acc[i][1], acc[i][2], acc[i][3]};
            float4 o1 = {acc[i][4], acc[i][5], acc[i][6], acc[i][7]};
            *(float4*)dst = o0;
            *(float4*)(dst + 4) = o1;
        }
    }
}

// ---------------------------------------------------------------------------
// fused B/C/D1 projection: bcd[M,160] = aConv[M,2048] @ [w_B;w_C;w_D1]^T
// 64x64 tile, 4x4 per thread, N=160 (grid.x = 3)
__global__ __launch_bounds__(256) void gemm_bcd(
    const float* __restrict__ A,
    const float* __restrict__ w_B, const float* __restrict__ w_C,
    const float* __restrict__ w_D1,
    float* __restrict__ Cm)
{
    __shared__ float As[16][68];
    __shared__ float Bs[16][68];
    const int tid = threadIdx.x;
    const int tx = tid & 15, ty = tid >> 4;
    const int row0 = blockIdx.y * 64, col0 = blockIdx.x * 64;
    const int K = D_MODEL;

    float acc[4][4];
#pragma unroll
    for (int i = 0; i < 4; i++)
#pragma unroll
        for (int j = 0; j < 4; j++) acc[i][j] = 0.f;

    for (int k0 = 0; k0 < K; k0 += 16) {
#pragma unroll
        for (int i = tid; i < 1024; i += 256) {
            int r = i >> 4, kk = i & 15;
            As[kk][r] = A[(size_t)(row0 + r) * D_MODEL + k0 + kk];
        }
#pragma unroll
        for (int i = tid; i < 1024; i += 256) {
            int c = i >> 4, kk = i & 15;
            int col = col0 + c;
            float v = 0.f;
            if (col < 16) v = w_B[(size_t)col * K + k0 + kk];
            else if (col < 32) v = w_C[(size_t)(col - 16) * K + k0 + kk];
            else if (col < 160) v = w_D1[(size_t)(col - 32) * K + k0 + kk];
            Bs[kk][c] = v;
        }
        __syncthreads();
#pragma unroll
        for (int kk = 0; kk < 16; kk++) {
            float a4[4], b4[4];
#pragma unroll
            for (int i = 0; i < 4; i++) a4[i] = As[kk][ty * 4 + i];
#pragma unroll
            for (int j = 0; j < 4; j++) b4[j] = Bs[kk][tx * 4 + j];
#pragma unroll
            for (int i = 0; i < 4; i++)
#pragma unroll
                for (int j = 0; j < 4; j++)
                    acc[i][j] = fmaf(a4[i], b4[j], acc[i][j]);
        }
        __syncthreads();
    }

#pragma unroll
    for (int i = 0; i < 4; i++) {
        int row = row0 + ty * 4 + i;
#pragma unroll
        for (int j = 0; j < 4; j++) {
            int col = col0 + tx * 4 + j;
            if (col < 160) Cm[(size_t)row * 160 + col] = acc[i][j];
        }
    }
}

// ---------------------------------------------------------------------------
// depthwise causal conv1d (K=4) + bias + SiLU
__global__ __launch_bounds__(256) void conv_silu(
    const float* __restrict__ ab,
    const float* __restrict__ cw, const float* __restrict__ cb,
    float* __restrict__ aConv)
{
    int idx = blockIdx.x * 256 + threadIdx.x;
    int d = idx & (D_MODEL - 1);
    int bl = idx >> 11;
    int l = bl & (LSEQ - 1);
    float w0 = cw[d * 4 + 0], w1 = cw[d * 4 + 1], w2 = cw[d * 4 + 2], w3 = cw[d * 4 + 3];
    const float* col = ab + (size_t)bl * 4096 + d;
    float acc = cb[d];
    acc = fmaf(col[0], w3, acc);
    if (l >= 1) acc = fmaf(*(col - 4096), w2, acc);
    if (l >= 2) acc = fmaf(*(col - 2 * 4096), w1, acc);
    if (l >= 3) acc = fmaf(*(col - 3 * 4096), w0, acc);
    aConv[idx] = siluf(acc);
}

// ---------------------------------------------------------------------------
// Chunk-parallel SSM scan. idx(b,c,s,d) = (((b*16+c)*16+s)<<11) + d
__global__ __launch_bounds__(256) void scan_phaseA(
    const float* __restrict__ delta, const float* __restrict__ aConv,
    const float* __restrict__ bcd, const float* __restrict__ A_param,
    float* __restrict__ hend, float* __restrict__ prod)
{
    int blk = blockIdx.x;                       // 0..255
    int d = ((blk & 7) << 8) + threadIdx.x;
    int c = (blk >> 3) & 15;
    int b = blk >> 7;
    float expA[16], h[16], p[16];
#pragma unroll
    for (int s = 0; s < 16; s++) {
        expA[s] = expf(-A_param[d * 16 + s]);
        h[s] = 0.f; p[s] = 1.f;
    }
    int r0 = b * LSEQ + c * CH;
    const float* dp = delta + (size_t)r0 * D_MODEL + d;
    const float* ap = aConv + (size_t)r0 * D_MODEL + d;
    const float4* bp = (const float4*)(bcd + (size_t)r0 * 160);
    for (int l = 0; l < CH; l++) {
        float dlt = *dp, av = *ap;
        float4 B0 = bp[0], B1 = bp[1], B2 = bp[2], B3 = bp[3];
        float Bv[16] = {B0.x, B0.y, B0.z, B0.w, B1.x, B1.y, B1.z, B1.w,
                        B2.x, B2.y, B2.z, B2.w, B3.x, B3.y, B3.z, B3.w};
        float x = dlt * av;
#pragma unroll
        for (int s = 0; s < 16; s++) {
            float Ab = expA[s] * dlt;
            h[s] = fmaf(Ab, h[s], Bv[s] * x);
            p[s] *= Ab;
        }
        dp += D_MODEL; ap += D_MODEL; bp += 10;
    }
    size_t base = ((size_t)(b * 16 + c) * 16 << 11) + d;
#pragma unroll
    for (int s = 0; s < 16; s++) {
        hend[base + ((size_t)s << 11)] = h[s];
        prod[base + ((size_t)s << 11)] = p[s];
    }
}

// chunk prefix: overwrite hend[c] with state ENTERING chunk c
__global__ __launch_bounds__(256) void scan_phaseB(
    float* __restrict__ hend, const float* __restrict__ prod)
{
    int t = blockIdx.x * 256 + threadIdx.x;     // 65536
    int d = t & 2047, s = (t >> 11) & 15, b = t >> 15;
    float h = 0.f;
    for (int c = 0; c < NCH; c++) {
        size_t idx = (((size_t)(b * 16 + c) * 16 + s) << 11) + d;
        float he = hend[idx], p = prod[idx];
        hend[idx] = h;
        h = fmaf(p, h, he);
    }
}

// replay with correct incoming state; fused C-contract + D-skip + gate.
// writes out in-place over delta.
__global__ __launch_bounds__(256) void scan_phaseC(
    float* __restrict__ delta, const float* __restrict__ aConv,
    const float* __restrict__ ab, const float* __restrict__ bcd,
    const float* __restrict__ A_param, const float* __restrict__ D_param,
    const float* __restrict__ hend)
{
    int blk = blockIdx.x;
    int d = ((blk & 7) << 8) + threadIdx.x;
    int c = (blk >> 3) & 15;
    int b = blk >> 7;
    float expA[16], h[16];
    size_t base = ((size_t)(b * 16 + c) * 16 << 11) + d;
#pragma unroll
    for (int s = 0; s < 16; s++) {
        expA[s] = expf(-A_param[d * 16 + s]);
        h[s] = hend[base + ((size_t)s << 11)];
    }
    float Dp = D_param[d];
    int r0 = b * LSEQ + c * CH;
    float* dp = delta + (size_t)r0 * D_MODEL + d;
    const float* ap = aConv + (size_t)r0 * D_MODEL + d;
    const float* gp = ab + (size_t)r0 * 4096 + D_MODEL + d;
    const float4* bp = (const float4*)(bcd + (size_t)r0 * 160);
    for (int l = 0; l < CH; l++) {
        float dlt = *dp, av = *ap, g = *gp;
        float4 B0 = bp[0], B1 = bp[1], B2 = bp[2], B3 = bp[3];
        float4 C0 = bp[4], C1 = bp[5], C2 = bp[6], C3 = bp[7];
        float Bv[16] = {B0.x, B0.y, B0.z, B0.w, B1.x, B1.y, B1.z, B1.w,
                        B2.x, B2.y, B2.z, B2.w, B3.x, B3.y, B3.z, B3.w};
        float Cv[16] = {C0.x, C0.y, C0.z, C0.w, C1.x, C1.y, C1.z, C1.w,
                        C2.x, C2.y, C2.z, C2.w, C3.x, C3.y, C3.z, C3.w};
        float x = dlt * av;
        float acc = 0.f;
#pragma unroll
        for (int s = 0; s < 16; s++) {
            float Ab = expA[s] * dlt;
            h[s] = fmaf(Ab, h[s], Bv[s] * x);
            acc = fmaf(h[s], Cv[s], acc);
        }
        *dp = (acc + Dp * av) * siluf(g);
        dp += D_MODEL; ap += D_MODEL; gp += 4096; bp += 10;
    }
}

extern "C" void kernel_launch(void* const* d_in, const int* in_sizes, int n_in,
                              void* d_out, int out_size, void* d_ws, size_t ws_size,
                              hipStream_t stream) {
    const float* seq = (const float*)d_in[0];
    const float* w_in = (const float*)d_in[1];
    const float* w_out = (const float*)d_in[2];
    const float* w_B = (const float*)d_in[3];
    const float* w_C = (const float*)d_in[4];
    const float* w_D1 = (const float*)d_in[5];
    const float* w_D2 = (const float*)d_in[6];
    const float* conv_w = (const float*)d_in[7];
    const float* conv_b = (const float*)d_in[8];
    const float* A_param = (const float*)d_in[9];
    const float* D_param = (const float*)d_in[10];
    float* out = (float*)d_out;

    // ws layout (floats): ab 32M | aConv 16M | bcd 1.25M | delta 16M | hend 4M | prod 4M
    float* ab = (float*)d_ws;
    float* aConv = ab + (size_t)MROWS * 4096;
    float* bcd = aConv + (size_t)MROWS * 2048;
    float* delta = bcd + (size_t)MROWS * 160;
    float* hend = delta + (size_t)MROWS * 2048;
    float* prod = hend + (size_t)4096 * NCH * 16;

    // 1) ab = seq @ w_in^T  [2048 x 4096], K=1024
    gemm128<<<dim3(32, 16), 256, 0, stream>>>(seq, D_INP, 0, w_in, ab, 4096,
                                              D_INP, nullptr, 0);
    // 2) depthwise conv + SiLU
    conv_silu<<<dim3((MROWS * D_MODEL) / 256), 256, 0, stream>>>(ab, conv_w, conv_b, aConv);
    // 3) fused B/C/D1 projection -> bcd [2048 x 160], K=2048
    gemm_bcd<<<dim3(3, 32), 256, 0, stream>>>(aConv, w_B, w_C, w_D1, bcd);
    // 4) delta = softplus(D_param + d1 @ w_D2^T)  [2048 x 2048], K=128
    gemm128<<<dim3(16, 16), 256, 0, stream>>>(bcd, 160, 32, w_D2, delta, D_MODEL,
                                              D_DISCR, D_param, 1);
    // 5) chunk-parallel scan (A: local scans, B: chunk prefix, C: replay+output)
    scan_phaseA<<<dim3(256), 256, 0, stream>>>(delta, aConv, bcd, A_param, hend, prod);
    scan_phaseB<<<dim3(256), 256, 0, stream>>>(hend, prod);
    scan_phaseC<<<dim3(256), 256, 0, stream>>>(delta, aConv, ab, bcd, A_param, D_param, hend);
    // 6) out = ssm_out @ w_out^T  [2048 x 1024], K=2048
    gemm128<<<dim3(8, 16), 256, 0, stream>>>(delta, D_MODEL, 0, w_out, out, D_INP,
                                             D_MODEL, nullptr, 0);
}

// Round 3
// 363.374 us; speedup vs baseline: 5.0047x; 2.5786x over previous
//
#include <hip/hip_runtime.h>
#include <math.h>

#define B_SZ 2
#define LSEQ 1024
#define D_INP 1024
#define D_MODEL 2048
#define D_STATE 16
#define D_DISCR 128
#define MROWS (B_SZ * LSEQ)
#define NCH 16
#define CH 64

typedef __bf16 bf16x8 __attribute__((ext_vector_type(8)));
typedef float f32x4 __attribute__((ext_vector_type(4)));
typedef unsigned short ushort8 __attribute__((ext_vector_type(8)));

__device__ __forceinline__ float siluf(float x) { return x / (1.f + expf(-x)); }
__device__ __forceinline__ float softplusf(float x) {
    return fmaxf(x, 0.f) + log1pf(expf(-fabsf(x)));
}
__device__ __forceinline__ unsigned short f2b(float f) {
    unsigned u = __builtin_bit_cast(unsigned, f);
    u = u + 0x7fffu + ((u >> 16) & 1u);
    return (unsigned short)(u >> 16);
}

// fp32 -> bf16 cast, 8 elems/thread, n must be multiple of 8
__global__ __launch_bounds__(256) void cast_bf16(
    const float* __restrict__ in, unsigned short* __restrict__ out, int n8)
{
    int i = blockIdx.x * 256 + threadIdx.x;
    if (i >= n8) return;
    const float4* p = (const float4*)(in + (size_t)i * 8);
    float4 a = p[0], b = p[1];
    ushort8 o = {f2b(a.x), f2b(a.y), f2b(a.z), f2b(a.w),
                 f2b(b.x), f2b(b.y), f2b(b.z), f2b(b.w)};
    *(ushort8*)(out + (size_t)i * 8) = o;
}

// ---------------------------------------------------------------------------
// bf16 MFMA GEMM-NT: C[M,N] = A[M,K] @ B[N,K]^T
// A bf16 row stride lda, B bf16 row stride K. M%128==0, K%32==0. N guarded.
// 128x128 tile, BK=32, 256 thr = 4 waves (2x2), 4x4 16x16x32 frags per wave.
// epi: 0 = fp32 C; 1 = bf16 C; 2 = softplus(bias+acc) fp32 C;
//      3 = bf16 C + fp32 copy of cols<32 into aux[row*32+col]
__global__ __launch_bounds__(256) void gemm_mfma(
    const unsigned short* __restrict__ A, int lda,
    const unsigned short* __restrict__ B,
    void* __restrict__ Cp, int ldc, int N, int K,
    const float* __restrict__ bias, float* __restrict__ aux, int epi)
{
    __shared__ unsigned short As[128 * 40];  // row stride 40 bf16 = 5 x 16B units
    __shared__ unsigned short Bs[128 * 40];
    const int t = threadIdx.x;
    const int row0 = blockIdx.y * 128, col0 = blockIdx.x * 128;
    const int lane = t & 63, wid = t >> 6;
    const int wm = wid >> 1, wn = wid & 1;
    const int fr = lane & 15, fq = lane >> 4;   // frag row/col, k-quad

    f32x4 acc[4][4];
#pragma unroll
    for (int i = 0; i < 4; i++)
#pragma unroll
        for (int j = 0; j < 4; j++) acc[i][j] = (f32x4){0.f, 0.f, 0.f, 0.f};

    // staging chunk coords: chunk c -> row c>>2, kq c&3 (8 bf16 per chunk)
    const int sr = t >> 2, sq = t & 3;

    for (int k0 = 0; k0 < K; k0 += 32) {
        ushort8 a0 = *(const ushort8*)(A + (size_t)(row0 + sr) * lda + k0 + sq * 8);
        ushort8 a1 = *(const ushort8*)(A + (size_t)(row0 + 64 + sr) * lda + k0 + sq * 8);
        ushort8 b0 = {0, 0, 0, 0, 0, 0, 0, 0}, b1 = {0, 0, 0, 0, 0, 0, 0, 0};
        if (col0 + sr < N)
            b0 = *(const ushort8*)(B + (size_t)(col0 + sr) * K + k0 + sq * 8);
        if (col0 + 64 + sr < N)
            b1 = *(const ushort8*)(B + (size_t)(col0 + 64 + sr) * K + k0 + sq * 8);
        __syncthreads();
        *(ushort8*)(As + sr * 40 + sq * 8) = a0;
        *(ushort8*)(As + (64 + sr) * 40 + sq * 8) = a1;
        *(ushort8*)(Bs + sr * 40 + sq * 8) = b0;
        *(ushort8*)(Bs + (64 + sr) * 40 + sq * 8) = b1;
        __syncthreads();

        bf16x8 af[4], bf[4];
#pragma unroll
        for (int i = 0; i < 4; i++) {
            ushort8 u = *(const ushort8*)(As + (wm * 64 + i * 16 + fr) * 40 + fq * 8);
            af[i] = __builtin_bit_cast(bf16x8, u);
        }
#pragma unroll
        for (int j = 0; j < 4; j++) {
            ushort8 u = *(const ushort8*)(Bs + (wn * 64 + j * 16 + fr) * 40 + fq * 8);
            bf[j] = __builtin_bit_cast(bf16x8, u);
        }
#pragma unroll
        for (int i = 0; i < 4; i++)
#pragma unroll
            for (int j = 0; j < 4; j++)
                acc[i][j] = __builtin_amdgcn_mfma_f32_16x16x32_bf16(
                    af[i], bf[j], acc[i][j], 0, 0, 0);
    }

    // epilogue: C/D layout col=lane&15, row=(lane>>4)*4+reg  [m89-verified]
    const int cr0 = row0 + wm * 64 + fq * 4;
    const int cc0 = col0 + wn * 64 + fr;
#pragma unroll
    for (int i = 0; i < 4; i++) {
#pragma unroll
        for (int j = 0; j < 4; j++) {
            int col = cc0 + j * 16;
            if (col >= N) continue;
#pragma unroll
            for (int r = 0; r < 4; r++) {
                int row = cr0 + i * 16 + r;
                float v = acc[i][j][r];
                if (epi == 0) {
                    ((float*)Cp)[(size_t)row * ldc + col] = v;
                } else if (epi == 1) {
                    ((unsigned short*)Cp)[(size_t)row * ldc + col] = f2b(v);
                } else if (epi == 2) {
                    ((float*)Cp)[(size_t)row * ldc + col] = softplusf(bias[col] + v);
                } else {
                    ((unsigned short*)Cp)[(size_t)row * ldc + col] = f2b(v);
                    if (col < 32) aux[(size_t)row * 32 + col] = v;
                }
            }
        }
    }
}

// ---------------------------------------------------------------------------
// depthwise causal conv1d (K=4) + bias + SiLU; fp32 out + bf16 out
__global__ __launch_bounds__(256) void conv_silu(
    const float* __restrict__ ab,
    const float* __restrict__ cw, const float* __restrict__ cb,
    float* __restrict__ aConv, unsigned short* __restrict__ aConvB)
{
    int idx = blockIdx.x * 256 + threadIdx.x;
    int d = idx & (D_MODEL - 1);
    int bl = idx >> 11;
    int l = bl & (LSEQ - 1);
    float w0 = cw[d * 4 + 0], w1 = cw[d * 4 + 1], w2 = cw[d * 4 + 2], w3 = cw[d * 4 + 3];
    const float* col = ab + (size_t)bl * 4096 + d;
    float acc = cb[d];
    acc = fmaf(col[0], w3, acc);
    if (l >= 1) acc = fmaf(*(col - 4096), w2, acc);
    if (l >= 2) acc = fmaf(*(col - 2 * 4096), w1, acc);
    if (l >= 3) acc = fmaf(*(col - 3 * 4096), w0, acc);
    float s = siluf(acc);
    aConv[idx] = s;
    aConvB[idx] = f2b(s);
}

// ---------------------------------------------------------------------------
// Chunk-parallel scan. bc32 is [MROWS, 32] fp32: B cols 0..15, C cols 16..31.
__global__ __launch_bounds__(256) void scan_phaseA(
    const float* __restrict__ delta, const float* __restrict__ aConv,
    const float* __restrict__ bc32, const float* __restrict__ A_param,
    float* __restrict__ hend, float* __restrict__ prod)
{
    int blk = blockIdx.x;
    int d = ((blk & 7) << 8) + threadIdx.x;
    int c = (blk >> 3) & 15;
    int b = blk >> 7;
    float expA[16], h[16], p[16];
#pragma unroll
    for (int s = 0; s < 16; s++) {
        expA[s] = expf(-A_param[d * 16 + s]);
        h[s] = 0.f; p[s] = 1.f;
    }
    int r0 = b * LSEQ + c * CH;
    const float* dp = delta + (size_t)r0 * D_MODEL + d;
    const float* ap = aConv + (size_t)r0 * D_MODEL + d;
    const float4* bp = (const float4*)(bc32 + (size_t)r0 * 32);
    for (int l = 0; l < CH; l++) {
        float dlt = *dp, av = *ap;
        float4 B0 = bp[0], B1 = bp[1], B2 = bp[2], B3 = bp[3];
        float Bv[16] = {B0.x, B0.y, B0.z, B0.w, B1.x, B1.y, B1.z, B1.w,
                        B2.x, B2.y, B2.z, B2.w, B3.x, B3.y, B3.z, B3.w};
        float x = dlt * av;
#pragma unroll
        for (int s = 0; s < 16; s++) {
            float Ab = expA[s] * dlt;
            h[s] = fmaf(Ab, h[s], Bv[s] * x);
            p[s] *= Ab;
        }
        dp += D_MODEL; ap += D_MODEL; bp += 8;
    }
    size_t base = ((size_t)(b * 16 + c) * 16 << 11) + d;
#pragma unroll
    for (int s = 0; s < 16; s++) {
        hend[base + ((size_t)s << 11)] = h[s];
        prod[base + ((size_t)s << 11)] = p[s];
    }
}

__global__ __launch_bounds__(256) void scan_phaseB(
    float* __restrict__ hend, const float* __restrict__ prod)
{
    int t = blockIdx.x * 256 + threadIdx.x;
    int d = t & 2047, s = (t >> 11) & 15, b = t >> 15;
    float h = 0.f;
    for (int c = 0; c < NCH; c++) {
        size_t idx = (((size_t)(b * 16 + c) * 16 + s) << 11) + d;
        float he = hend[idx], p = prod[idx];
        hend[idx] = h;
        h = fmaf(p, h, he);
    }
}

// replay + C-contract + D-skip + gate -> bf16 out (feeds final GEMM)
__global__ __launch_bounds__(256) void scan_phaseC(
    const float* __restrict__ delta, const float* __restrict__ aConv,
    const float* __restrict__ ab, const float* __restrict__ bc32,
    const float* __restrict__ A_param, const float* __restrict__ D_param,
    const float* __restrict__ hend, unsigned short* __restrict__ outB)
{
    int blk = blockIdx.x;
    int d = ((blk & 7) << 8) + threadIdx.x;
    int c = (blk >> 3) & 15;
    int b = blk >> 7;
    float expA[16], h[16];
    size_t base = ((size_t)(b * 16 + c) * 16 << 11) + d;
#pragma unroll
    for (int s = 0; s < 16; s++) {
        expA[s] = expf(-A_param[d * 16 + s]);
        h[s] = hend[base + ((size_t)s << 11)];
    }
    float Dp = D_param[d];
    int r0 = b * LSEQ + c * CH;
    const float* dp = delta + (size_t)r0 * D_MODEL + d;
    const float* ap = aConv + (size_t)r0 * D_MODEL + d;
    const float* gp = ab + (size_t)r0 * 4096 + D_MODEL + d;
    const float4* bp = (const float4*)(bc32 + (size_t)r0 * 32);
    unsigned short* op = outB + (size_t)r0 * D_MODEL + d;
    for (int l = 0; l < CH; l++) {
        float dlt = *dp, av = *ap, g = *gp;
        float4 B0 = bp[0], B1 = bp[1], B2 = bp[2], B3 = bp[3];
        float4 C0 = bp[4], C1 = bp[5], C2 = bp[6], C3 = bp[7];
        float Bv[16] = {B0.x, B0.y, B0.z, B0.w, B1.x, B1.y, B1.z, B1.w,
                        B2.x, B2.y, B2.z, B2.w, B3.x, B3.y, B3.z, B3.w};
        float Cv[16] = {C0.x, C0.y, C0.z, C0.w, C1.x, C1.y, C1.z, C1.w,
                        C2.x, C2.y, C2.z, C2.w, C3.x, C3.y, C3.z, C3.w};
        float x = dlt * av;
        float acc = 0.f;
#pragma unroll
        for (int s = 0; s < 16; s++) {
            float Ab = expA[s] * dlt;
            h[s] = fmaf(Ab, h[s], Bv[s] * x);
            acc = fmaf(h[s], Cv[s], acc);
        }
        *op = f2b((acc + Dp * av) * siluf(g));
        dp += D_MODEL; ap += D_MODEL; gp += 4096; bp += 8; op += D_MODEL;
    }
}

extern "C" void kernel_launch(void* const* d_in, const int* in_sizes, int n_in,
                              void* d_out, int out_size, void* d_ws, size_t ws_size,
                              hipStream_t stream) {
    const float* seq = (const float*)d_in[0];
    const float* w_in = (const float*)d_in[1];
    const float* w_out = (const float*)d_in[2];
    const float* w_B = (const float*)d_in[3];
    const float* w_C = (const float*)d_in[4];
    const float* w_D1 = (const float*)d_in[5];
    const float* w_D2 = (const float*)d_in[6];
    const float* conv_w = (const float*)d_in[7];
    const float* conv_b = (const float*)d_in[8];
    const float* A_param = (const float*)d_in[9];
    const float* D_param = (const float*)d_in[10];
    float* out = (float*)d_out;

    // fp32 region
    float* ab      = (float*)d_ws;               // 2048*4096
    float* aConv32 = ab + (size_t)8388608;       // 2048*2048
    float* delta   = aConv32 + (size_t)4194304;  // 2048*2048
    float* bc32    = delta + (size_t)4194304;    // 2048*32
    float* hend    = bc32 + (size_t)65536;       // 1048576
    float* prod    = hend + (size_t)1048576;     // 1048576
    // bf16 region
    unsigned short* seq_b  = (unsigned short*)(prod + 1048576);
    unsigned short* win_b  = seq_b + (size_t)2097152;
    unsigned short* wout_b = win_b + (size_t)4194304;
    unsigned short* wbcd_b = wout_b + (size_t)2097152;  // [160, 2048]
    unsigned short* wd2_b  = wbcd_b + (size_t)327680;   // [2048, 128]
    unsigned short* aConvB = wd2_b + (size_t)262144;    // [2048, 2048]
    unsigned short* bcdB   = aConvB + (size_t)4194304;  // [2048, 160]
    unsigned short* outB   = bcdB + (size_t)327680;     // [2048, 2048]

    // 0) casts to bf16
    cast_bf16<<<dim3(1024), 256, 0, stream>>>(seq, seq_b, 262144);
    cast_bf16<<<dim3(2048), 256, 0, stream>>>(w_in, win_b, 524288);
    cast_bf16<<<dim3(1024), 256, 0, stream>>>(w_out, wout_b, 262144);
    cast_bf16<<<dim3(16), 256, 0, stream>>>(w_B, wbcd_b, 4096);
    cast_bf16<<<dim3(16), 256, 0, stream>>>(w_C, wbcd_b + 32768, 4096);
    cast_bf16<<<dim3(128), 256, 0, stream>>>(w_D1, wbcd_b + 65536, 32768);
    cast_bf16<<<dim3(128), 256, 0, stream>>>(w_D2, wd2_b, 32768);

    // 1) ab = seq @ w_in^T  [2048 x 4096] K=1024, fp32 out
    gemm_mfma<<<dim3(32, 16), 256, 0, stream>>>(seq_b, 1024, win_b, ab, 4096,
                                                4096, 1024, nullptr, nullptr, 0);
    // 2) conv + SiLU (fp32 + bf16 outputs)
    conv_silu<<<dim3(16384), 256, 0, stream>>>(ab, conv_w, conv_b, aConv32, aConvB);
    // 3) bcd = aConv @ [wB;wC;wD1]^T  [2048 x 160] K=2048; bf16 + fp32 B/C copy
    gemm_mfma<<<dim3(2, 16), 256, 0, stream>>>(aConvB, 2048, wbcd_b, bcdB, 160,
                                               160, 2048, nullptr, bc32, 3);
    // 4) delta = softplus(D + d1 @ wD2^T)  [2048 x 2048] K=128, fp32 out
    gemm_mfma<<<dim3(16, 16), 256, 0, stream>>>(bcdB + 32, 160, wd2_b, delta, 2048,
                                                2048, 128, D_param, nullptr, 2);
    // 5) chunk-parallel scan
    scan_phaseA<<<dim3(256), 256, 0, stream>>>(delta, aConv32, bc32, A_param, hend, prod);
    scan_phaseB<<<dim3(256), 256, 0, stream>>>(hend, prod);
    scan_phaseC<<<dim3(256), 256, 0, stream>>>(delta, aConv32, ab, bc32, A_param,
                                               D_param, hend, outB);
    // 6) out = ssm_out @ w_out^T  [2048 x 1024] K=2048, fp32 out
    gemm_mfma<<<dim3(8, 16), 256, 0, stream>>>(outB, 2048, wout_b, out, 1024,
                                               1024, 2048, nullptr, nullptr, 0);
}